// Round 1
// baseline (835.670 us; speedup 1.0000x reference)
//
#include <hip/hip_runtime.h>
#include <hip/hip_bf16.h>

#define BATCH 256
#define TSTEPS 1024
#define NIN 128
#define NL 64
#define NH 128
#define NOUT 32

typedef __attribute__((ext_vector_type(8))) short short8;
typedef __attribute__((ext_vector_type(4))) float f32x4;

__device__ inline int pk2(float x, float y) {
    __hip_bfloat162 h = __float22bfloat162_rn(make_float2(x, y));
    union { __hip_bfloat162 h; int i; } u;
    u.h = h;
    return u.i;
}
__device__ inline short bf1(float x) {
    __hip_bfloat16 h = __float2bfloat16(x);
    union { __hip_bfloat16 h; short s; } u;
    u.h = h;
    return u.s;
}

// compiler-only ordering fence: no instruction emitted, prevents TBAA
// reordering of LDS write/read pairs (same-wave DS ops execute in order in HW)
#define KFENCE() asm volatile("" ::: "memory")

// ---------------------------------------------------------------------------
// Pass 1: u'[t][b][l] = bf16( C[l,:]·s[b,t,:] + h1[l] )   (unchanged)
// ---------------------------------------------------------------------------
__launch_bounds__(256, 1)
__global__ void ugemm_mfma(const float* __restrict__ input,
                           const float* __restrict__ C,
                           const float* __restrict__ h1,
                           unsigned short* __restrict__ u16) {
    const int lane = threadIdx.x & 63;
    const int wv   = threadIdx.x >> 6;
    const int c = lane & 15;
    const int q = lane >> 4;
    const long wbase = ((long)blockIdx.x * 4 + wv) * 128;  // first row (b*1024+t)

    short8 cA[4][4];
    #pragma unroll
    for (int mt = 0; mt < 4; ++mt)
        #pragma unroll
        for (int kf = 0; kf < 4; ++kf) {
            const float* p = C + (mt * 16 + c) * NIN + kf * 32 + q * 8;
            float4 r0 = *(const float4*)p;
            float4 r1 = *(const float4*)(p + 4);
            union { short8 s; int i[4]; } f;
            f.i[0] = pk2(r0.x, r0.y); f.i[1] = pk2(r0.z, r0.w);
            f.i[2] = pk2(r1.x, r1.y); f.i[3] = pk2(r1.z, r1.w);
            cA[mt][kf] = f.s;
        }
    f32x4 h1f[4];
    #pragma unroll
    for (int mt = 0; mt < 4; ++mt)
        h1f[mt] = *(const f32x4*)(h1 + mt * 16 + q * 4);

    float4 raw[8], rawn[8];
    {
        const float* sr = input + (wbase + c) * NIN;
        #pragma unroll
        for (int kf = 0; kf < 4; ++kf) {
            raw[2*kf]   = *(const float4*)(sr + kf * 32 + q * 8);
            raw[2*kf+1] = *(const float4*)(sr + kf * 32 + q * 8 + 4);
        }
    }

    for (int it = 0; it < 8; ++it) {
        if (it < 7) {
            const float* sr = input + (wbase + (it + 1) * 16 + c) * NIN;
            #pragma unroll
            for (int kf = 0; kf < 4; ++kf) {
                rawn[2*kf]   = *(const float4*)(sr + kf * 32 + q * 8);
                rawn[2*kf+1] = *(const float4*)(sr + kf * 32 + q * 8 + 4);
            }
        }
        short8 bf[4];
        #pragma unroll
        for (int kf = 0; kf < 4; ++kf) {
            union { short8 s; int i[4]; } f;
            f.i[0] = pk2(raw[2*kf].x,   raw[2*kf].y);
            f.i[1] = pk2(raw[2*kf].z,   raw[2*kf].w);
            f.i[2] = pk2(raw[2*kf+1].x, raw[2*kf+1].y);
            f.i[3] = pk2(raw[2*kf+1].z, raw[2*kf+1].w);
            bf[kf] = f.s;
        }
        long rr = wbase + it * 16 + c;
        int b = (int)(rr >> 10), t = (int)(rr & 1023);
        unsigned short* ubase = u16 + ((size_t)t * 256 + b) * 64 + q * 4;
        #pragma unroll
        for (int mt = 0; mt < 4; ++mt) {
            f32x4 acc = __builtin_amdgcn_mfma_f32_16x16x32_bf16(cA[mt][0], bf[0], h1f[mt], 0, 0, 0);
            acc = __builtin_amdgcn_mfma_f32_16x16x32_bf16(cA[mt][1], bf[1], acc, 0, 0, 0);
            acc = __builtin_amdgcn_mfma_f32_16x16x32_bf16(cA[mt][2], bf[2], acc, 0, 0, 0);
            acc = __builtin_amdgcn_mfma_f32_16x16x32_bf16(cA[mt][3], bf[3], acc, 0, 0, 0);
            *(int2*)(ubase + mt * 16) =
                make_int2(pk2(acc[0], acc[1]), pk2(acc[2], acc[3]));
        }
        #pragma unroll
        for (int j = 0; j < 8; ++j) raw[j] = rawn[j];
    }
}

// ---------------------------------------------------------------------------
// Pass 2: barrier-free scan. ONE wave owns 16 batches and computes the full
// recurrence (all 128 H rows + all 64 Z rows). D->B fragment redistribution
// stays within the wave -> intra-wave LDS round-trip, no s_barrier, only
// compiler-inserted lgkmcnt waits (DS ops of one wave execute in order).
// Grid 16 x 64: one wave per CU.
// ---------------------------------------------------------------------------
__launch_bounds__(64, 1)
__global__ void plrnn_scan_wave(const float* __restrict__ A,
                                const float* __restrict__ W1,
                                const float* __restrict__ W2,
                                const float* __restrict__ h2,
                                const unsigned short* __restrict__ u16,
                                const float* __restrict__ Wout,
                                const float* __restrict__ bout,
                                float* __restrict__ out) {
    __shared__ __attribute__((aligned(16))) unsigned short zs[16 * 72];
    __shared__ __attribute__((aligned(16))) unsigned short hs[16 * 136];

    const int lane = threadIdx.x & 63;
    const int c = lane & 15;               // batch column
    const int q = lane >> 4;               // quad
    const int bbase = blockIdx.x * 16;

    // ---- static weight fragments (whole model per wave) ----
    short8 aw2[8][2];                      // W2: 8 M-tiles x K=64 (2 frags)
    #pragma unroll
    for (int mt = 0; mt < 8; ++mt)
        #pragma unroll
        for (int kt = 0; kt < 2; ++kt) {
            const float* p = W2 + (mt * 16 + c) * NL + kt * 32 + q * 8;
            short8 f;
            #pragma unroll
            for (int j = 0; j < 8; ++j) f[j] = bf1(p[j]);
            aw2[mt][kt] = f;
        }
    short8 aw1[4][4];                      // W1: 4 M-tiles x K=128 (4 frags)
    #pragma unroll
    for (int lt = 0; lt < 4; ++lt)
        #pragma unroll
        for (int kt = 0; kt < 4; ++kt) {
            const float* p = W1 + (lt * 16 + c) * NH + kt * 32 + q * 8;
            short8 f;
            #pragma unroll
            for (int j = 0; j < 8; ++j) f[j] = bf1(p[j]);
            aw1[lt][kt] = f;
        }
    f32x4 h2f[8];
    #pragma unroll
    for (int mt = 0; mt < 8; ++mt)
        h2f[mt] = *(const f32x4*)(h2 + mt * 16 + q * 4);
    f32x4 af[4];
    #pragma unroll
    for (int lt = 0; lt < 4; ++lt)
        af[lt] = *(const f32x4*)(A + lt * 16 + q * 4);

    // u' stream: (t*256 + b)*64 + l ; per-lane base, 4 int2 per step
    const unsigned short* ub = u16 + (size_t)(bbase + c) * 64 + q * 4;
    int2 uP[4], uQ[4];
    #pragma unroll
    for (int lt = 0; lt < 4; ++lt) {
        uP[lt] = *(const int2*)(ub + lt * 16);              // u(0)
        uQ[lt] = *(const int2*)(ub + 16384 + lt * 16);      // u(1)
    }

    f32x4 zf[4];
    #pragma unroll
    for (int lt = 0; lt < 4; ++lt) zf[lt] = (f32x4){0.f, 0.f, 0.f, 0.f};

    // z0 = 0 -> B-fragments are just zero, no LDS round-trip needed
    short8 bz0 = (short8){0, 0, 0, 0, 0, 0, 0, 0};
    short8 bz1 = (short8){0, 0, 0, 0, 0, 0, 0, 0};

    // cin(t=0) = u(0)   (A*z0 = 0)
    f32x4 cin[4];
    #pragma unroll
    for (int lt = 0; lt < 4; ++lt) {
        cin[lt][0] = __int_as_float(uP[lt].x << 16);
        cin[lt][1] = __int_as_float(uP[lt].x & 0xffff0000);
        cin[lt][2] = __int_as_float(uP[lt].y << 16);
        cin[lt][3] = __int_as_float(uP[lt].y & 0xffff0000);
    }

    // one timestep; pf <- prefetch target (u(T+2)), tail <- u(T+1) for next cin
    auto step = [&](int2 (&pf)[4], const int2 (&tail)[4], const int T) {
        // ---- MFMA1 lower half: H tiles 0..3, frag-major for 4-way ILP ----
        f32x4 ha[4];
        #pragma unroll
        for (int mt = 0; mt < 4; ++mt)
            ha[mt] = __builtin_amdgcn_mfma_f32_16x16x32_bf16(aw2[mt][0], bz0, h2f[mt], 0, 0, 0);
        #pragma unroll
        for (int mt = 0; mt < 4; ++mt)
            ha[mt] = __builtin_amdgcn_mfma_f32_16x16x32_bf16(aw2[mt][1], bz1, ha[mt], 0, 0, 0);
        #pragma unroll
        for (int mt = 0; mt < 4; ++mt)
            *(int2*)&hs[c * 136 + mt * 16 + q * 4] = make_int2(
                pk2(fmaxf(ha[mt][0], 0.f), fmaxf(ha[mt][1], 0.f)),
                pk2(fmaxf(ha[mt][2], 0.f), fmaxf(ha[mt][3], 0.f)));
        KFENCE();
        short8 bh0 = *(short8*)&hs[c * 136 + q * 8];
        short8 bh1 = *(short8*)&hs[c * 136 + 32 + q * 8];

        // ---- MFMA1 upper half: H tiles 4..7 (hides bh0/bh1 read latency) ----
        f32x4 hb[4];
        #pragma unroll
        for (int mt = 0; mt < 4; ++mt)
            hb[mt] = __builtin_amdgcn_mfma_f32_16x16x32_bf16(aw2[mt + 4][0], bz0, h2f[mt + 4], 0, 0, 0);
        #pragma unroll
        for (int mt = 0; mt < 4; ++mt)
            hb[mt] = __builtin_amdgcn_mfma_f32_16x16x32_bf16(aw2[mt + 4][1], bz1, hb[mt], 0, 0, 0);
        #pragma unroll
        for (int mt = 0; mt < 4; ++mt)
            *(int2*)&hs[c * 136 + (mt + 4) * 16 + q * 4] = make_int2(
                pk2(fmaxf(hb[mt][0], 0.f), fmaxf(hb[mt][1], 0.f)),
                pk2(fmaxf(hb[mt][2], 0.f), fmaxf(hb[mt][3], 0.f)));
        KFENCE();
        short8 bh2 = *(short8*)&hs[c * 136 + 64 + q * 8];
        short8 bh3 = *(short8*)&hs[c * 136 + 96 + q * 8];

        // prefetch u(T+2) into pf (consumed at tail of NEXT step -> no copies)
        const int tp = (T + 2 < TSTEPS) ? T + 2 : TSTEPS - 1;
        #pragma unroll
        for (int lt = 0; lt < 4; ++lt)
            pf[lt] = *(const int2*)(ub + (size_t)tp * 16384 + lt * 16);

        // ---- MFMA2: Z' tiles 0..3, frag-major (4 chains of depth 4) ----
        f32x4 za[4];
        #pragma unroll
        for (int lt = 0; lt < 4; ++lt)
            za[lt] = __builtin_amdgcn_mfma_f32_16x16x32_bf16(aw1[lt][0], bh0, cin[lt], 0, 0, 0);
        #pragma unroll
        for (int lt = 0; lt < 4; ++lt)
            za[lt] = __builtin_amdgcn_mfma_f32_16x16x32_bf16(aw1[lt][1], bh1, za[lt], 0, 0, 0);
        #pragma unroll
        for (int lt = 0; lt < 4; ++lt)
            za[lt] = __builtin_amdgcn_mfma_f32_16x16x32_bf16(aw1[lt][2], bh2, za[lt], 0, 0, 0);
        #pragma unroll
        for (int lt = 0; lt < 4; ++lt)
            za[lt] = __builtin_amdgcn_mfma_f32_16x16x32_bf16(aw1[lt][3], bh3, za[lt], 0, 0, 0);

        // clip -> zf, publish z', re-read as B-frags for next step
        #pragma unroll
        for (int lt = 0; lt < 4; ++lt) {
            zf[lt][0] = __builtin_amdgcn_fmed3f(za[lt][0], -5.f, 5.f);
            zf[lt][1] = __builtin_amdgcn_fmed3f(za[lt][1], -5.f, 5.f);
            zf[lt][2] = __builtin_amdgcn_fmed3f(za[lt][2], -5.f, 5.f);
            zf[lt][3] = __builtin_amdgcn_fmed3f(za[lt][3], -5.f, 5.f);
        }
        #pragma unroll
        for (int lt = 0; lt < 4; ++lt)
            *(int2*)&zs[c * 72 + lt * 16 + q * 4] =
                make_int2(pk2(zf[lt][0], zf[lt][1]), pk2(zf[lt][2], zf[lt][3]));
        KFENCE();
        bz0 = *(short8*)&zs[c * 72 + q * 8];
        bz1 = *(short8*)&zs[c * 72 + 32 + q * 8];

        // next cin = A*z' + u(T+1)  (VALU work hides the bz read latency)
        #pragma unroll
        for (int lt = 0; lt < 4; ++lt) {
            cin[lt][0] = fmaf(zf[lt][0], af[lt][0], __int_as_float(tail[lt].x << 16));
            cin[lt][1] = fmaf(zf[lt][1], af[lt][1], __int_as_float(tail[lt].x & 0xffff0000));
            cin[lt][2] = fmaf(zf[lt][2], af[lt][2], __int_as_float(tail[lt].y << 16));
            cin[lt][3] = fmaf(zf[lt][3], af[lt][3], __int_as_float(tail[lt].y & 0xffff0000));
        }
    };

    for (int t = 0; t < TSTEPS; t += 2) {
        step(uP, uQ, t);       // even: prefetch->uP, tail uses uQ = u(t+1)
        step(uQ, uP, t + 1);   // odd:  prefetch->uQ, tail uses uP = u(t+2)
    }

    // ---- epilogue: out = Wout @ z_T + bout (bz0/bz1 hold z_T B-frags) ----
    short8 wo[2][2];
    #pragma unroll
    for (int ot = 0; ot < 2; ++ot)
        #pragma unroll
        for (int kt = 0; kt < 2; ++kt) {
            const float* p = Wout + (ot * 16 + c) * NL + kt * 32 + q * 8;
            short8 f;
            #pragma unroll
            for (int j = 0; j < 8; ++j) f[j] = bf1(p[j]);
            wo[ot][kt] = f;
        }
    #pragma unroll
    for (int ot = 0; ot < 2; ++ot) {
        f32x4 ob = *(const f32x4*)(bout + ot * 16 + q * 4);
        f32x4 acc = __builtin_amdgcn_mfma_f32_16x16x32_bf16(wo[ot][0], bz0, ob, 0, 0, 0);
        acc = __builtin_amdgcn_mfma_f32_16x16x32_bf16(wo[ot][1], bz1, acc, 0, 0, 0);
        *(f32x4*)&out[(size_t)(bbase + c) * 32 + ot * 16 + q * 4] = acc;
    }
}

extern "C" void kernel_launch(void* const* d_in, const int* in_sizes, int n_in,
                              void* d_out, int out_size, void* d_ws, size_t ws_size,
                              hipStream_t stream) {
    const float* input = (const float*)d_in[0];
    const float* A     = (const float*)d_in[1];
    const float* W1    = (const float*)d_in[2];
    const float* W2    = (const float*)d_in[3];
    const float* h1    = (const float*)d_in[4];
    const float* h2    = (const float*)d_in[5];
    const float* C     = (const float*)d_in[6];
    const float* Wout  = (const float*)d_in[7];
    const float* bout  = (const float*)d_in[8];
    float* out = (float*)d_out;

    unsigned short* u16 = (unsigned short*)d_ws;   // 256*1024*64 bf16 = 33.5 MB

    ugemm_mfma<<<dim3(512), dim3(256), 0, stream>>>(input, C, h1, u16);
    plrnn_scan_wave<<<dim3(16), dim3(64), 0, stream>>>(
        A, W1, W2, h2, u16, Wout, bout, out);
}

// Round 2
// 788.126 us; speedup vs baseline: 1.0603x; 1.0603x over previous
//
#include <hip/hip_runtime.h>
#include <hip/hip_bf16.h>

#define BATCH 256
#define TSTEPS 1024
#define NIN 128
#define NL 64
#define NH 128
#define NOUT 32

typedef __attribute__((ext_vector_type(8))) short short8;
typedef __attribute__((ext_vector_type(4))) float f32x4;
typedef __attribute__((ext_vector_type(2))) unsigned int u32x2;

__device__ inline int pk2(float x, float y) {
    __hip_bfloat162 h = __float22bfloat162_rn(make_float2(x, y));
    union { __hip_bfloat162 h; int i; } u;
    u.h = h;
    return u.i;
}
__device__ inline short bf1(float x) {
    __hip_bfloat16 h = __float2bfloat16(x);
    union { __hip_bfloat16 h; short s; } u;
    u.h = h;
    return u.s;
}

// ---------------------------------------------------------------------------
// In-register D->B fragment redistribution for 16x16x32 bf16 MFMA.
// D gives lane (c,q) rows q*4..q*4+3 (as 2 pk2 ints); B-frag needs rows
// q*8..q*8+7 of a 32-row group (2 consecutive 16-row tiles). This is a pure
// permutation within lane groups {c, c+16, c+32, c+48}:
//   permlane32_swap + permlane16_swap, 2x per pk-component = 4 VALU ops.
// a0,a1 = P0,P1 of even tile; b0,b1 = P0,P1 of odd tile.
// ---------------------------------------------------------------------------
__device__ inline short8 mk_bfrag(int a0, int a1, int b0, int b1) {
    u32x2 s0 = __builtin_amdgcn_permlane32_swap((unsigned)a0, (unsigned)b0, false, false);
    u32x2 t0 = __builtin_amdgcn_permlane16_swap(s0[0], s0[1], false, false);
    u32x2 s1 = __builtin_amdgcn_permlane32_swap((unsigned)a1, (unsigned)b1, false, false);
    u32x2 t1 = __builtin_amdgcn_permlane16_swap(s1[0], s1[1], false, false);
    union { int i[4]; short8 s; } u;
    u.i[0] = (int)t0[0];   // rows q*8+0..1
    u.i[1] = (int)t1[0];   // rows q*8+2..3
    u.i[2] = (int)t0[1];   // rows q*8+4..5
    u.i[3] = (int)t1[1];   // rows q*8+6..7
    return u.s;
}

// ---------------------------------------------------------------------------
// Pass 1: u'[t][b][l] = bf16( C[l,:]·s[b,t,:] + h1[l] )   (unchanged)
// ---------------------------------------------------------------------------
__launch_bounds__(256, 1)
__global__ void ugemm_mfma(const float* __restrict__ input,
                           const float* __restrict__ C,
                           const float* __restrict__ h1,
                           unsigned short* __restrict__ u16) {
    const int lane = threadIdx.x & 63;
    const int wv   = threadIdx.x >> 6;
    const int c = lane & 15;
    const int q = lane >> 4;
    const long wbase = ((long)blockIdx.x * 4 + wv) * 128;  // first row (b*1024+t)

    short8 cA[4][4];
    #pragma unroll
    for (int mt = 0; mt < 4; ++mt)
        #pragma unroll
        for (int kf = 0; kf < 4; ++kf) {
            const float* p = C + (mt * 16 + c) * NIN + kf * 32 + q * 8;
            float4 r0 = *(const float4*)p;
            float4 r1 = *(const float4*)(p + 4);
            union { short8 s; int i[4]; } f;
            f.i[0] = pk2(r0.x, r0.y); f.i[1] = pk2(r0.z, r0.w);
            f.i[2] = pk2(r1.x, r1.y); f.i[3] = pk2(r1.z, r1.w);
            cA[mt][kf] = f.s;
        }
    f32x4 h1f[4];
    #pragma unroll
    for (int mt = 0; mt < 4; ++mt)
        h1f[mt] = *(const f32x4*)(h1 + mt * 16 + q * 4);

    float4 raw[8], rawn[8];
    {
        const float* sr = input + (wbase + c) * NIN;
        #pragma unroll
        for (int kf = 0; kf < 4; ++kf) {
            raw[2*kf]   = *(const float4*)(sr + kf * 32 + q * 8);
            raw[2*kf+1] = *(const float4*)(sr + kf * 32 + q * 8 + 4);
        }
    }

    for (int it = 0; it < 8; ++it) {
        if (it < 7) {
            const float* sr = input + (wbase + (it + 1) * 16 + c) * NIN;
            #pragma unroll
            for (int kf = 0; kf < 4; ++kf) {
                rawn[2*kf]   = *(const float4*)(sr + kf * 32 + q * 8);
                rawn[2*kf+1] = *(const float4*)(sr + kf * 32 + q * 8 + 4);
            }
        }
        short8 bf[4];
        #pragma unroll
        for (int kf = 0; kf < 4; ++kf) {
            union { short8 s; int i[4]; } f;
            f.i[0] = pk2(raw[2*kf].x,   raw[2*kf].y);
            f.i[1] = pk2(raw[2*kf].z,   raw[2*kf].w);
            f.i[2] = pk2(raw[2*kf+1].x, raw[2*kf+1].y);
            f.i[3] = pk2(raw[2*kf+1].z, raw[2*kf+1].w);
            bf[kf] = f.s;
        }
        long rr = wbase + it * 16 + c;
        int b = (int)(rr >> 10), t = (int)(rr & 1023);
        unsigned short* ubase = u16 + ((size_t)t * 256 + b) * 64 + q * 4;
        #pragma unroll
        for (int mt = 0; mt < 4; ++mt) {
            f32x4 acc = __builtin_amdgcn_mfma_f32_16x16x32_bf16(cA[mt][0], bf[0], h1f[mt], 0, 0, 0);
            acc = __builtin_amdgcn_mfma_f32_16x16x32_bf16(cA[mt][1], bf[1], acc, 0, 0, 0);
            acc = __builtin_amdgcn_mfma_f32_16x16x32_bf16(cA[mt][2], bf[2], acc, 0, 0, 0);
            acc = __builtin_amdgcn_mfma_f32_16x16x32_bf16(cA[mt][3], bf[3], acc, 0, 0, 0);
            *(int2*)(ubase + mt * 16) =
                make_int2(pk2(acc[0], acc[1]), pk2(acc[2], acc[3]));
        }
        #pragma unroll
        for (int j = 0; j < 8; ++j) raw[j] = rawn[j];
    }
}

// ---------------------------------------------------------------------------
// Pass 2: single-wave scan, ZERO LDS. D->B redistribution done in-register
// via permlane32_swap/permlane16_swap (4 VALU ops per 32-row group). No
// barriers, no lgkmcnt drains on the serial chain. Grid 16 x 64.
// ---------------------------------------------------------------------------
__launch_bounds__(64, 1)
__global__ void plrnn_scan_wave(const float* __restrict__ A,
                                const float* __restrict__ W1,
                                const float* __restrict__ W2,
                                const float* __restrict__ h2,
                                const unsigned short* __restrict__ u16,
                                const float* __restrict__ Wout,
                                const float* __restrict__ bout,
                                float* __restrict__ out) {
    const int lane = threadIdx.x & 63;
    const int c = lane & 15;               // batch column
    const int q = lane >> 4;               // quad
    const int bbase = blockIdx.x * 16;

    // ---- static weight fragments (whole model per wave) ----
    short8 aw2[8][2];                      // W2: 8 M-tiles x K=64 (2 frags)
    #pragma unroll
    for (int mt = 0; mt < 8; ++mt)
        #pragma unroll
        for (int kt = 0; kt < 2; ++kt) {
            const float* p = W2 + (mt * 16 + c) * NL + kt * 32 + q * 8;
            short8 f;
            #pragma unroll
            for (int j = 0; j < 8; ++j) f[j] = bf1(p[j]);
            aw2[mt][kt] = f;
        }
    short8 aw1[4][4];                      // W1: 4 M-tiles x K=128 (4 frags)
    #pragma unroll
    for (int lt = 0; lt < 4; ++lt)
        #pragma unroll
        for (int kt = 0; kt < 4; ++kt) {
            const float* p = W1 + (lt * 16 + c) * NH + kt * 32 + q * 8;
            short8 f;
            #pragma unroll
            for (int j = 0; j < 8; ++j) f[j] = bf1(p[j]);
            aw1[lt][kt] = f;
        }
    f32x4 h2f[8];
    #pragma unroll
    for (int mt = 0; mt < 8; ++mt)
        h2f[mt] = *(const f32x4*)(h2 + mt * 16 + q * 4);
    f32x4 af[4];
    #pragma unroll
    for (int lt = 0; lt < 4; ++lt)
        af[lt] = *(const f32x4*)(A + lt * 16 + q * 4);

    // u' stream: (t*256 + b)*64 + l ; per-lane base, 4 int2 per step
    const unsigned short* ub = u16 + (size_t)(bbase + c) * 64 + q * 4;
    int2 uP[4], uQ[4];
    #pragma unroll
    for (int lt = 0; lt < 4; ++lt) {
        uP[lt] = *(const int2*)(ub + lt * 16);              // u(0)
        uQ[lt] = *(const int2*)(ub + 16384 + lt * 16);      // u(1)
    }

    f32x4 zf[4];
    #pragma unroll
    for (int lt = 0; lt < 4; ++lt) zf[lt] = (f32x4){0.f, 0.f, 0.f, 0.f};

    // z0 = 0 -> B-fragments are zero
    short8 bz0 = (short8){0, 0, 0, 0, 0, 0, 0, 0};
    short8 bz1 = (short8){0, 0, 0, 0, 0, 0, 0, 0};

    // cin(t=0) = u(0)   (A*z0 = 0)
    f32x4 cin[4];
    #pragma unroll
    for (int lt = 0; lt < 4; ++lt) {
        cin[lt][0] = __int_as_float(uP[lt].x << 16);
        cin[lt][1] = __int_as_float(uP[lt].x & 0xffff0000);
        cin[lt][2] = __int_as_float(uP[lt].y << 16);
        cin[lt][3] = __int_as_float(uP[lt].y & 0xffff0000);
    }

    // one timestep; pf <- prefetch target (u(T+2)), tail <- u(T+1) for next cin
    auto step = [&](int2 (&pf)[4], const int2 (&tail)[4], const int T) {
        // ---- MFMA1: all 8 H tiles, frag-major (8 chains, depth 2) ----
        f32x4 ha[8];
        #pragma unroll
        for (int mt = 0; mt < 8; ++mt)
            ha[mt] = __builtin_amdgcn_mfma_f32_16x16x32_bf16(aw2[mt][0], bz0, h2f[mt], 0, 0, 0);
        #pragma unroll
        for (int mt = 0; mt < 8; ++mt)
            ha[mt] = __builtin_amdgcn_mfma_f32_16x16x32_bf16(aw2[mt][1], bz1, ha[mt], 0, 0, 0);

        // relu + pack to pk2 pairs
        int hp[8][2];
        #pragma unroll
        for (int mt = 0; mt < 8; ++mt) {
            hp[mt][0] = pk2(fmaxf(ha[mt][0], 0.f), fmaxf(ha[mt][1], 0.f));
            hp[mt][1] = pk2(fmaxf(ha[mt][2], 0.f), fmaxf(ha[mt][3], 0.f));
        }
        // in-register redistribution -> B-frags (no LDS)
        short8 bh0 = mk_bfrag(hp[0][0], hp[0][1], hp[1][0], hp[1][1]);
        short8 bh1 = mk_bfrag(hp[2][0], hp[2][1], hp[3][0], hp[3][1]);
        short8 bh2 = mk_bfrag(hp[4][0], hp[4][1], hp[5][0], hp[5][1]);
        short8 bh3 = mk_bfrag(hp[6][0], hp[6][1], hp[7][0], hp[7][1]);

        // prefetch u(T+2) into pf (consumed at tail of NEXT step -> no copies)
        const int tp = (T + 2 < TSTEPS) ? T + 2 : TSTEPS - 1;
        #pragma unroll
        for (int lt = 0; lt < 4; ++lt)
            pf[lt] = *(const int2*)(ub + (size_t)tp * 16384 + lt * 16);

        // ---- MFMA2: Z' tiles 0..3, frag-major (4 chains, depth 4) ----
        f32x4 za[4];
        #pragma unroll
        for (int lt = 0; lt < 4; ++lt)
            za[lt] = __builtin_amdgcn_mfma_f32_16x16x32_bf16(aw1[lt][0], bh0, cin[lt], 0, 0, 0);
        #pragma unroll
        for (int lt = 0; lt < 4; ++lt)
            za[lt] = __builtin_amdgcn_mfma_f32_16x16x32_bf16(aw1[lt][1], bh1, za[lt], 0, 0, 0);
        #pragma unroll
        for (int lt = 0; lt < 4; ++lt)
            za[lt] = __builtin_amdgcn_mfma_f32_16x16x32_bf16(aw1[lt][2], bh2, za[lt], 0, 0, 0);
        #pragma unroll
        for (int lt = 0; lt < 4; ++lt)
            za[lt] = __builtin_amdgcn_mfma_f32_16x16x32_bf16(aw1[lt][3], bh3, za[lt], 0, 0, 0);

        // clip -> zf, pack, redistribute -> next bz frags (no LDS)
        int zp[4][2];
        #pragma unroll
        for (int lt = 0; lt < 4; ++lt) {
            zf[lt][0] = __builtin_amdgcn_fmed3f(za[lt][0], -5.f, 5.f);
            zf[lt][1] = __builtin_amdgcn_fmed3f(za[lt][1], -5.f, 5.f);
            zf[lt][2] = __builtin_amdgcn_fmed3f(za[lt][2], -5.f, 5.f);
            zf[lt][3] = __builtin_amdgcn_fmed3f(za[lt][3], -5.f, 5.f);
            zp[lt][0] = pk2(zf[lt][0], zf[lt][1]);
            zp[lt][1] = pk2(zf[lt][2], zf[lt][3]);
        }
        bz0 = mk_bfrag(zp[0][0], zp[0][1], zp[1][0], zp[1][1]);
        bz1 = mk_bfrag(zp[2][0], zp[2][1], zp[3][0], zp[3][1]);

        // next cin = A*z' + u(T+1)
        #pragma unroll
        for (int lt = 0; lt < 4; ++lt) {
            cin[lt][0] = fmaf(zf[lt][0], af[lt][0], __int_as_float(tail[lt].x << 16));
            cin[lt][1] = fmaf(zf[lt][1], af[lt][1], __int_as_float(tail[lt].x & 0xffff0000));
            cin[lt][2] = fmaf(zf[lt][2], af[lt][2], __int_as_float(tail[lt].y << 16));
            cin[lt][3] = fmaf(zf[lt][3], af[lt][3], __int_as_float(tail[lt].y & 0xffff0000));
        }
    };

    for (int t = 0; t < TSTEPS; t += 2) {
        step(uP, uQ, t);       // even: prefetch->uP, tail uses uQ = u(t+1)
        step(uQ, uP, t + 1);   // odd:  prefetch->uQ, tail uses uP = u(t+2)
    }

    // ---- epilogue: out = Wout @ z_T + bout (bz0/bz1 hold z_T B-frags) ----
    short8 wo[2][2];
    #pragma unroll
    for (int ot = 0; ot < 2; ++ot)
        #pragma unroll
        for (int kt = 0; kt < 2; ++kt) {
            const float* p = Wout + (ot * 16 + c) * NL + kt * 32 + q * 8;
            short8 f;
            #pragma unroll
            for (int j = 0; j < 8; ++j) f[j] = bf1(p[j]);
            wo[ot][kt] = f;
        }
    #pragma unroll
    for (int ot = 0; ot < 2; ++ot) {
        f32x4 ob = *(const f32x4*)(bout + ot * 16 + q * 4);
        f32x4 acc = __builtin_amdgcn_mfma_f32_16x16x32_bf16(wo[ot][0], bz0, ob, 0, 0, 0);
        acc = __builtin_amdgcn_mfma_f32_16x16x32_bf16(wo[ot][1], bz1, acc, 0, 0, 0);
        *(f32x4*)&out[(size_t)(bbase + c) * 32 + ot * 16 + q * 4] = acc;
    }
}

extern "C" void kernel_launch(void* const* d_in, const int* in_sizes, int n_in,
                              void* d_out, int out_size, void* d_ws, size_t ws_size,
                              hipStream_t stream) {
    const float* input = (const float*)d_in[0];
    const float* A     = (const float*)d_in[1];
    const float* W1    = (const float*)d_in[2];
    const float* W2    = (const float*)d_in[3];
    const float* h1    = (const float*)d_in[4];
    const float* h2    = (const float*)d_in[5];
    const float* C     = (const float*)d_in[6];
    const float* Wout  = (const float*)d_in[7];
    const float* bout  = (const float*)d_in[8];
    float* out = (float*)d_out;

    unsigned short* u16 = (unsigned short*)d_ws;   // 256*1024*64 bf16 = 33.5 MB

    ugemm_mfma<<<dim3(512), dim3(256), 0, stream>>>(input, C, h1, u16);
    plrnn_scan_wave<<<dim3(16), dim3(64), 0, stream>>>(
        A, W1, W2, h2, u16, Wout, bout, out);
}